// Round 2
// baseline (1069.089 us; speedup 1.0000x reference)
//
#include <hip/hip_runtime.h>
#include <hip/hip_bf16.h>

#define N_NODES 50000
#define DIM 128
#define N_GRAPHS 64
#define E_RAW 800000
#define E_TOT 850000
#define NEG_SLOPE 0.2f

__device__ __forceinline__ unsigned enc_f32(float f) {
    unsigned u = __float_as_uint(f);
    return (u & 0x80000000u) ? ~u : (u | 0x80000000u);
}
__device__ __forceinline__ float dec_f32(unsigned v) {
    return (v & 0x80000000u) ? __uint_as_float(v ^ 0x80000000u) : __uint_as_float(~v);
}
#define ENC_NEG_INF 0x007FFFFFu

__global__ void zero_kernel(int* deg, int* fillc, float* pooled,
                            unsigned* menc3, float* ssum3) {
    int i = blockIdx.x * blockDim.x + threadIdx.x;
    if (i < N_NODES) { deg[i] = 0; fillc[i] = 0; }
    if (i < N_GRAPHS * DIM) pooled[i] = 0.f;
    if (i < 3 * N_NODES) { menc3[i] = ENC_NEG_INF; ssum3[i] = 0.f; }
}

__global__ void count_kernel(const int* __restrict__ ei, int* __restrict__ deg) {
    int e = blockIdx.x * blockDim.x + threadIdx.x;
    if (e >= E_TOT) return;
    int dst = (e < E_RAW) ? ei[E_RAW + e] : (e - E_RAW);
    atomicAdd(&deg[dst], 1);
}

__global__ void scan1_kernel(const int* __restrict__ deg, int* __restrict__ excl,
                             int* __restrict__ blksum, int n) {
    __shared__ int lds[256];
    int t = threadIdx.x;
    int i = blockIdx.x * 256 + t;
    int v = (i < n) ? deg[i] : 0;
    lds[t] = v;
    __syncthreads();
    int incl = v;
    for (int off = 1; off < 256; off <<= 1) {
        int y = (t >= off) ? lds[t - off] : 0;
        __syncthreads();
        incl += y;
        lds[t] = incl;
        __syncthreads();
    }
    if (i < n) excl[i] = incl - v;
    if (t == 255) blksum[blockIdx.x] = incl;
}

__global__ void scan2_kernel(int* __restrict__ blksum, int nblk) {
    __shared__ int lds[256];
    int t = threadIdx.x;
    int v = (t < nblk) ? blksum[t] : 0;
    lds[t] = v;
    __syncthreads();
    int incl = v;
    for (int off = 1; off < 256; off <<= 1) {
        int y = (t >= off) ? lds[t - off] : 0;
        __syncthreads();
        incl += y;
        lds[t] = incl;
        __syncthreads();
    }
    if (t < nblk) blksum[t] = incl - v;
}

__global__ void scan3_kernel(int* __restrict__ row_ptr, const int* __restrict__ blksum, int n) {
    int i = blockIdx.x * blockDim.x + threadIdx.x;
    if (i < n) row_ptr[i] += blksum[i >> 8];
    if (i == 0) row_ptr[n] = E_TOT;
}

__global__ void fill_kernel(const int* __restrict__ ei, const int* __restrict__ row_ptr,
                            int* __restrict__ fillc, int* __restrict__ csr_src,
                            int* __restrict__ csr_pos) {
    int e = blockIdx.x * blockDim.x + threadIdx.x;
    if (e >= E_TOT) return;
    int src, dst;
    if (e < E_RAW) { src = ei[e]; dst = ei[E_RAW + e]; }
    else           { src = dst = e - E_RAW; }
    int slot = row_ptr[dst] + atomicAdd(&fillc[dst], 1);
    csr_src[slot] = src;
    csr_pos[e] = slot;
}

// GEMM + fused attention dots
__global__ __launch_bounds__(256) void gemm_dots_kernel(
    const float* __restrict__ X, const float* __restrict__ W,
    const float* __restrict__ asrc, const float* __restrict__ adst,
    float* __restrict__ H, float* __restrict__ s1, float* __restrict__ s2, int nrows) {
    __shared__ float Wl[DIM][DIM];
    int t = threadIdx.x;
    for (int i = t; i < DIM * DIM / 4; i += 256)
        ((float4*)&Wl[0][0])[i] = ((const float4*)W)[i];
    __syncthreads();

    int tx = t & 15, ty = t >> 4;
    int row0 = blockIdx.x * 128 + ty * 8;
    int col0 = tx * 8;
    float acc[8][8];
#pragma unroll
    for (int r = 0; r < 8; ++r)
#pragma unroll
        for (int c = 0; c < 8; ++c) acc[r][c] = 0.f;

    for (int k = 0; k < DIM; k += 4) {
        float4 xr[8];
#pragma unroll
        for (int r = 0; r < 8; ++r) {
            int row = row0 + r;
            xr[r] = (row < nrows) ? *(const float4*)&X[row * DIM + k]
                                  : make_float4(0.f, 0.f, 0.f, 0.f);
        }
#pragma unroll
        for (int kk = 0; kk < 4; ++kk) {
            float w0[8];
#pragma unroll
            for (int c = 0; c < 8; ++c) w0[c] = Wl[k + kk][col0 + c];
#pragma unroll
            for (int r = 0; r < 8; ++r) {
                float xv = (kk == 0) ? xr[r].x : (kk == 1) ? xr[r].y : (kk == 2) ? xr[r].z : xr[r].w;
#pragma unroll
                for (int c = 0; c < 8; ++c) acc[r][c] = fmaf(xv, w0[c], acc[r][c]);
            }
        }
    }

    float a1r[8], a2r[8];
#pragma unroll
    for (int c = 0; c < 8; ++c) { a1r[c] = asrc[col0 + c]; a2r[c] = adst[col0 + c]; }

#pragma unroll
    for (int r = 0; r < 8; ++r) {
        int row = row0 + r;
        if (row < nrows) {
#pragma unroll
            for (int c = 0; c < 8; c += 4) {
                *(float4*)&H[row * DIM + col0 + c] =
                    make_float4(acc[r][c], acc[r][c + 1], acc[r][c + 2], acc[r][c + 3]);
            }
        }
        float p1 = 0.f, p2 = 0.f;
#pragma unroll
        for (int c = 0; c < 8; ++c) { p1 = fmaf(acc[r][c], a1r[c], p1); p2 = fmaf(acc[r][c], a2r[c], p2); }
#pragma unroll
        for (int m = 1; m < 16; m <<= 1) { p1 += __shfl_xor(p1, m); p2 += __shfl_xor(p2, m); }
        if (tx == 0 && row < nrows) { s1[row] = p1; s2[row] = p2; }
    }
}

__global__ void edge1_kernel(const int* __restrict__ ei, const float* __restrict__ s1,
                             const float* __restrict__ s2, float* __restrict__ alpha,
                             unsigned* __restrict__ menc) {
    int e = blockIdx.x * blockDim.x + threadIdx.x;
    if (e >= E_TOT) return;
    int src, dst;
    if (e < E_RAW) { src = ei[e]; dst = ei[E_RAW + e]; }
    else           { src = dst = e - E_RAW; }
    float a = s1[src] + s2[dst];
    a = (a > 0.f) ? a : NEG_SLOPE * a;
    alpha[e] = a;
    atomicMax(&menc[dst], enc_f32(a));
}

__global__ void edge2_kernel(const int* __restrict__ ei, const float* __restrict__ alpha,
                             const unsigned* __restrict__ menc, float* __restrict__ ssum,
                             const int* __restrict__ csr_pos, float* __restrict__ wcsr) {
    int e = blockIdx.x * blockDim.x + threadIdx.x;
    if (e >= E_TOT) return;
    int dst = (e < E_RAW) ? ei[E_RAW + e] : (e - E_RAW);
    float m = dec_f32(menc[dst]);
    float ev = __expf(alpha[e] - m);
    atomicAdd(&ssum[dst], ev);
    wcsr[csr_pos[e]] = ev;
}

// aggregation: 32 lanes per node, float4 rows, 4 gathers in flight
__global__ __launch_bounds__(256) void agg_kernel(
    const float4* __restrict__ H4, const float* __restrict__ wcsr,
    const int* __restrict__ csr_src, const int* __restrict__ row_ptr,
    const float* __restrict__ ssum, const float* __restrict__ bias,
    float4* __restrict__ Xout4, const int* __restrict__ batch,
    float* __restrict__ pooled, int pool_flag, int n) {
    int g = blockIdx.x * blockDim.x + threadIdx.x;
    int node = g >> 5;
    int lane = threadIdx.x & 31;
    if (node >= n) return;
    int beg = row_ptr[node], end = row_ptr[node + 1];
    float inv = 1.f / (ssum[node] + 1e-16f);
    int base = (threadIdx.x & 32);

    float4 acc = make_float4(0.f, 0.f, 0.f, 0.f);

    for (int c = beg; c < end; c += 32) {
        int m = end - c; if (m > 32) m = 32;
        int sn_v = 0; float w_v = 0.f;
        if (lane < m) { sn_v = csr_src[c + lane]; w_v = wcsr[c + lane]; }
        int j = 0;
        for (; j + 4 <= m; j += 4) {
            int i0 = __shfl(sn_v, base + j);
            int i1 = __shfl(sn_v, base + j + 1);
            int i2 = __shfl(sn_v, base + j + 2);
            int i3 = __shfl(sn_v, base + j + 3);
            float w0 = __shfl(w_v, base + j);
            float w1 = __shfl(w_v, base + j + 1);
            float w2 = __shfl(w_v, base + j + 2);
            float w3 = __shfl(w_v, base + j + 3);
            float4 h0 = H4[(size_t)i0 * 32 + lane];
            float4 h1 = H4[(size_t)i1 * 32 + lane];
            float4 h2 = H4[(size_t)i2 * 32 + lane];
            float4 h3 = H4[(size_t)i3 * 32 + lane];
            acc.x = fmaf(w0, h0.x, acc.x); acc.y = fmaf(w0, h0.y, acc.y);
            acc.z = fmaf(w0, h0.z, acc.z); acc.w = fmaf(w0, h0.w, acc.w);
            acc.x = fmaf(w1, h1.x, acc.x); acc.y = fmaf(w1, h1.y, acc.y);
            acc.z = fmaf(w1, h1.z, acc.z); acc.w = fmaf(w1, h1.w, acc.w);
            acc.x = fmaf(w2, h2.x, acc.x); acc.y = fmaf(w2, h2.y, acc.y);
            acc.z = fmaf(w2, h2.z, acc.z); acc.w = fmaf(w2, h2.w, acc.w);
            acc.x = fmaf(w3, h3.x, acc.x); acc.y = fmaf(w3, h3.y, acc.y);
            acc.z = fmaf(w3, h3.z, acc.z); acc.w = fmaf(w3, h3.w, acc.w);
        }
        for (; j < m; ++j) {
            int i0 = __shfl(sn_v, base + j);
            float w0 = __shfl(w_v, base + j);
            float4 h0 = H4[(size_t)i0 * 32 + lane];
            acc.x = fmaf(w0, h0.x, acc.x); acc.y = fmaf(w0, h0.y, acc.y);
            acc.z = fmaf(w0, h0.z, acc.z); acc.w = fmaf(w0, h0.w, acc.w);
        }
    }

    float4 b4 = ((const float4*)bias)[lane];
    acc.x = fmaxf(fmaf(acc.x, inv, b4.x), 0.f);
    acc.y = fmaxf(fmaf(acc.y, inv, b4.y), 0.f);
    acc.z = fmaxf(fmaf(acc.z, inv, b4.z), 0.f);
    acc.w = fmaxf(fmaf(acc.w, inv, b4.w), 0.f);
    Xout4[(size_t)node * 32 + lane] = acc;
    if (pool_flag) {
        int g2 = batch[node];
        atomicAdd(&pooled[g2 * DIM + lane * 4 + 0], acc.x);
        atomicAdd(&pooled[g2 * DIM + lane * 4 + 1], acc.y);
        atomicAdd(&pooled[g2 * DIM + lane * 4 + 2], acc.z);
        atomicAdd(&pooled[g2 * DIM + lane * 4 + 3], acc.w);
    }
}

__global__ void final_kernel(const float* __restrict__ pooled, const float* __restrict__ Wf,
                             const float* __restrict__ bf, float* __restrict__ y) {
    int wid = (blockIdx.x * blockDim.x + threadIdx.x) >> 6;
    int lane = threadIdx.x & 63;
    if (wid >= N_GRAPHS) return;
    float2 p = *(const float2*)&pooled[wid * DIM + 2 * lane];
    float2 w = *(const float2*)&Wf[2 * lane];
    float v = p.x * w.x + p.y * w.y;
    for (int off = 32; off; off >>= 1) v += __shfl_down(v, off);
    if (lane == 0) y[wid] = v + bf[0];
}

extern "C" void kernel_launch(void* const* d_in, const int* in_sizes, int n_in,
                              void* d_out, int out_size, void* d_ws, size_t ws_size,
                              hipStream_t stream) {
    const float* x       = (const float*)d_in[0];
    const int*   ei      = (const int*)d_in[1];
    const int*   batch   = (const int*)d_in[2];
    const float* Ws      = (const float*)d_in[3];
    const float* att_src = (const float*)d_in[4];
    const float* att_dst = (const float*)d_in[5];
    const float* biases  = (const float*)d_in[6];
    const float* Wf      = (const float*)d_in[7];
    const float* bf      = (const float*)d_in[8];
    float* y = (float*)d_out;

    char* p = (char*)d_ws;
    auto alloc = [&](size_t bytes) -> void* {
        void* r = (void*)p;
        p += (bytes + 255) & ~(size_t)255;
        return r;
    };
    float* xA      = (float*)alloc((size_t)N_NODES * DIM * 4);
    float* xB      = (float*)alloc((size_t)N_NODES * DIM * 4);
    float* h       = (float*)alloc((size_t)N_NODES * DIM * 4);
    float* alphab  = (float*)alloc((size_t)E_TOT * 4);
    float* wcsr    = (float*)alloc((size_t)E_TOT * 4);
    int*   csr_src = (int*)alloc((size_t)E_TOT * 4);
    int*   csr_pos = (int*)alloc((size_t)E_TOT * 4);
    int*   deg     = (int*)alloc((size_t)N_NODES * 4);
    int*   fillc   = (int*)alloc((size_t)N_NODES * 4);
    int*   row_ptr = (int*)alloc((size_t)(N_NODES + 1) * 4);
    int*   blksum  = (int*)alloc(256 * 4);
    unsigned* menc3 = (unsigned*)alloc((size_t)3 * N_NODES * 4);
    float* ssum3   = (float*)alloc((size_t)3 * N_NODES * 4);
    float* pooled  = (float*)alloc((size_t)N_GRAPHS * DIM * 4);
    float* s1      = (float*)alloc((size_t)N_NODES * 4);
    float* s2      = (float*)alloc((size_t)N_NODES * 4);

    const int BN = 256;
    const int gN   = (N_NODES + BN - 1) / BN;
    const int gE   = (E_TOT + BN - 1) / BN;
    const int gI   = (3 * N_NODES + BN - 1) / BN;
    const int gAGG = (N_NODES * 32 + BN - 1) / BN;
    const int nblk = gN;

    zero_kernel<<<gI, BN, 0, stream>>>(deg, fillc, pooled, menc3, ssum3);
    count_kernel<<<gE, BN, 0, stream>>>(ei, deg);
    scan1_kernel<<<nblk, BN, 0, stream>>>(deg, row_ptr, blksum, N_NODES);
    scan2_kernel<<<1, BN, 0, stream>>>(blksum, nblk);
    scan3_kernel<<<gN, BN, 0, stream>>>(row_ptr, blksum, N_NODES);
    fill_kernel<<<gE, BN, 0, stream>>>(ei, row_ptr, fillc, csr_src, csr_pos);

    const float* xin = x;
    float* xout = xA;
    for (int l = 0; l < 3; ++l) {
        const float* W  = Ws + (size_t)l * DIM * DIM;
        const float* as = att_src + (size_t)l * DIM;
        const float* ad = att_dst + (size_t)l * DIM;
        const float* b  = biases + (size_t)l * DIM;
        unsigned* menc = menc3 + (size_t)l * N_NODES;
        float* ssum    = ssum3 + (size_t)l * N_NODES;

        gemm_dots_kernel<<<(N_NODES + 127) / 128, BN, 0, stream>>>(xin, W, as, ad, h, s1, s2, N_NODES);
        edge1_kernel<<<gE, BN, 0, stream>>>(ei, s1, s2, alphab, menc);
        edge2_kernel<<<gE, BN, 0, stream>>>(ei, alphab, menc, ssum, csr_pos, wcsr);
        agg_kernel<<<gAGG, BN, 0, stream>>>((const float4*)h, wcsr, csr_src, row_ptr,
                                            ssum, b, (float4*)xout, batch, pooled,
                                            (l == 2) ? 1 : 0, N_NODES);
        xin = xout;
        xout = (l == 0) ? xB : xA;
    }

    final_kernel<<<(N_GRAPHS * 64 + BN - 1) / BN, BN, 0, stream>>>(pooled, Wf, bf, y);
    (void)ws_size; (void)n_in; (void)in_sizes; (void)out_size;
}

// Round 3
// 942.107 us; speedup vs baseline: 1.1348x; 1.1348x over previous
//
#include <hip/hip_runtime.h>
#include <hip/hip_bf16.h>

#define N_NODES 50000
#define DIM 128
#define N_GRAPHS 64
#define E_RAW 800000
#define E_TOT 850000
#define NEG_SLOPE 0.2f

__device__ __forceinline__ unsigned enc_f32(float f) {
    unsigned u = __float_as_uint(f);
    return (u & 0x80000000u) ? ~u : (u | 0x80000000u);
}
__device__ __forceinline__ float dec_f32(unsigned v) {
    return (v & 0x80000000u) ? __uint_as_float(v ^ 0x80000000u) : __uint_as_float(~v);
}
#define ENC_NEG_INF 0x007FFFFFu

__global__ void zero_kernel(int* deg, int* fillc, float* pooled,
                            unsigned* menc3, float* ssum3) {
    int i = blockIdx.x * blockDim.x + threadIdx.x;
    if (i < N_NODES) { deg[i] = 0; fillc[i] = 0; }
    if (i < N_GRAPHS * DIM) pooled[i] = 0.f;
    if (i < 3 * N_NODES) { menc3[i] = ENC_NEG_INF; ssum3[i] = 0.f; }
}

__global__ void count_kernel(const int* __restrict__ ei, int* __restrict__ deg) {
    int e = blockIdx.x * blockDim.x + threadIdx.x;
    if (e >= E_TOT) return;
    int dst = (e < E_RAW) ? ei[E_RAW + e] : (e - E_RAW);
    atomicAdd(&deg[dst], 1);
}

__global__ void scan1_kernel(const int* __restrict__ deg, int* __restrict__ excl,
                             int* __restrict__ blksum, int n) {
    __shared__ int lds[256];
    int t = threadIdx.x;
    int i = blockIdx.x * 256 + t;
    int v = (i < n) ? deg[i] : 0;
    lds[t] = v;
    __syncthreads();
    int incl = v;
    for (int off = 1; off < 256; off <<= 1) {
        int y = (t >= off) ? lds[t - off] : 0;
        __syncthreads();
        incl += y;
        lds[t] = incl;
        __syncthreads();
    }
    if (i < n) excl[i] = incl - v;
    if (t == 255) blksum[blockIdx.x] = incl;
}

__global__ void scan2_kernel(int* __restrict__ blksum, int nblk) {
    __shared__ int lds[256];
    int t = threadIdx.x;
    int v = (t < nblk) ? blksum[t] : 0;
    lds[t] = v;
    __syncthreads();
    int incl = v;
    for (int off = 1; off < 256; off <<= 1) {
        int y = (t >= off) ? lds[t - off] : 0;
        __syncthreads();
        incl += y;
        lds[t] = incl;
        __syncthreads();
    }
    if (t < nblk) blksum[t] = incl - v;
}

__global__ void scan3_kernel(int* __restrict__ row_ptr, const int* __restrict__ blksum, int n) {
    int i = blockIdx.x * blockDim.x + threadIdx.x;
    if (i < n) row_ptr[i] += blksum[i >> 8];
    if (i == 0) row_ptr[n] = E_TOT;
}

__global__ void fill_kernel(const int* __restrict__ ei, const int* __restrict__ row_ptr,
                            int* __restrict__ fillc, int* __restrict__ csr_src,
                            int* __restrict__ csr_pos) {
    int e = blockIdx.x * blockDim.x + threadIdx.x;
    if (e >= E_TOT) return;
    int src, dst;
    if (e < E_RAW) { src = ei[e]; dst = ei[E_RAW + e]; }
    else           { src = dst = e - E_RAW; }
    int slot = row_ptr[dst] + atomicAdd(&fillc[dst], 1);
    csr_src[slot] = src;
    csr_pos[e] = slot;
}

// GEMM + fused attention dots
__global__ __launch_bounds__(256) void gemm_dots_kernel(
    const float* __restrict__ X, const float* __restrict__ W,
    const float* __restrict__ asrc, const float* __restrict__ adst,
    float* __restrict__ H, float* __restrict__ s1, float* __restrict__ s2, int nrows) {
    __shared__ float Wl[DIM][DIM];
    int t = threadIdx.x;
    for (int i = t; i < DIM * DIM / 4; i += 256)
        ((float4*)&Wl[0][0])[i] = ((const float4*)W)[i];
    __syncthreads();

    int tx = t & 15, ty = t >> 4;
    int row0 = blockIdx.x * 128 + ty * 8;
    int col0 = tx * 8;
    float acc[8][8];
#pragma unroll
    for (int r = 0; r < 8; ++r)
#pragma unroll
        for (int c = 0; c < 8; ++c) acc[r][c] = 0.f;

    for (int k = 0; k < DIM; k += 4) {
        float4 xr[8];
#pragma unroll
        for (int r = 0; r < 8; ++r) {
            int row = row0 + r;
            xr[r] = (row < nrows) ? *(const float4*)&X[row * DIM + k]
                                  : make_float4(0.f, 0.f, 0.f, 0.f);
        }
#pragma unroll
        for (int kk = 0; kk < 4; ++kk) {
            float w0[8];
#pragma unroll
            for (int c = 0; c < 8; ++c) w0[c] = Wl[k + kk][col0 + c];
#pragma unroll
            for (int r = 0; r < 8; ++r) {
                float xv = (kk == 0) ? xr[r].x : (kk == 1) ? xr[r].y : (kk == 2) ? xr[r].z : xr[r].w;
#pragma unroll
                for (int c = 0; c < 8; ++c) acc[r][c] = fmaf(xv, w0[c], acc[r][c]);
            }
        }
    }

    float a1r[8], a2r[8];
#pragma unroll
    for (int c = 0; c < 8; ++c) { a1r[c] = asrc[col0 + c]; a2r[c] = adst[col0 + c]; }

#pragma unroll
    for (int r = 0; r < 8; ++r) {
        int row = row0 + r;
        if (row < nrows) {
#pragma unroll
            for (int c = 0; c < 8; c += 4) {
                *(float4*)&H[row * DIM + col0 + c] =
                    make_float4(acc[r][c], acc[r][c + 1], acc[r][c + 2], acc[r][c + 3]);
            }
        }
        float p1 = 0.f, p2 = 0.f;
#pragma unroll
        for (int c = 0; c < 8; ++c) { p1 = fmaf(acc[r][c], a1r[c], p1); p2 = fmaf(acc[r][c], a2r[c], p2); }
#pragma unroll
        for (int m = 1; m < 16; m <<= 1) { p1 += __shfl_xor(p1, m); p2 += __shfl_xor(p2, m); }
        if (tx == 0 && row < nrows) { s1[row] = p1; s2[row] = p2; }
    }
}

__global__ void edge1_kernel(const int* __restrict__ ei, const float* __restrict__ s1,
                             const float* __restrict__ s2, float* __restrict__ alpha,
                             unsigned* __restrict__ menc) {
    int e = blockIdx.x * blockDim.x + threadIdx.x;
    if (e >= E_TOT) return;
    int src, dst;
    if (e < E_RAW) { src = ei[e]; dst = ei[E_RAW + e]; }
    else           { src = dst = e - E_RAW; }
    float a = s1[src] + s2[dst];
    a = (a > 0.f) ? a : NEG_SLOPE * a;
    alpha[e] = a;
    atomicMax(&menc[dst], enc_f32(a));
}

__global__ void edge2_kernel(const int* __restrict__ ei, const float* __restrict__ alpha,
                             const unsigned* __restrict__ menc, float* __restrict__ ssum,
                             const int* __restrict__ csr_pos, float* __restrict__ wcsr) {
    int e = blockIdx.x * blockDim.x + threadIdx.x;
    if (e >= E_TOT) return;
    int dst = (e < E_RAW) ? ei[E_RAW + e] : (e - E_RAW);
    float m = dec_f32(menc[dst]);
    float ev = __expf(alpha[e] - m);
    atomicAdd(&ssum[dst], ev);
    wcsr[csr_pos[e]] = ev;
}

// aggregation: one wave (64 lanes) per dst node, float2/lane, 8 gathers in flight.
// w/sn loads are wave-uniform broadcast loads (no shuffles -> no lgkm deps between
// metadata and gather addresses). Predicated 8-wide tail (sn=0 row gather is cheap,
// w=0 makes the fma a no-op) so there is no serial remainder loop.
__global__ __launch_bounds__(256) void agg_kernel(
    const float2* __restrict__ H2, const float* __restrict__ wcsr,
    const int* __restrict__ csr_src, const int* __restrict__ row_ptr,
    const float* __restrict__ ssum, const float* __restrict__ bias,
    float2* __restrict__ Xout2, const int* __restrict__ batch,
    float* __restrict__ pooled, int pool_flag, int n) {
    int wid = (blockIdx.x * blockDim.x + threadIdx.x) >> 6;
    int lane = threadIdx.x & 63;
    if (wid >= n) return;
    int beg = row_ptr[wid], end = row_ptr[wid + 1];
    float inv = 1.f / (ssum[wid] + 1e-16f);
    float2 acc = make_float2(0.f, 0.f);

    for (int s = beg; s < end; s += 8) {
        float w[8]; int sn[8];
#pragma unroll
        for (int j = 0; j < 8; ++j) {
            int idx = s + j;
            bool v = idx < end;
            w[j]  = v ? wcsr[idx] : 0.f;
            sn[j] = v ? csr_src[idx] : 0;
        }
        float2 hv[8];
#pragma unroll
        for (int j = 0; j < 8; ++j) hv[j] = H2[(size_t)sn[j] * 64 + lane];
#pragma unroll
        for (int j = 0; j < 8; ++j) {
            acc.x = fmaf(w[j], hv[j].x, acc.x);
            acc.y = fmaf(w[j], hv[j].y, acc.y);
        }
    }

    float2 b2 = ((const float2*)bias)[lane];
    acc.x = fmaxf(fmaf(acc.x, inv, b2.x), 0.f);
    acc.y = fmaxf(fmaf(acc.y, inv, b2.y), 0.f);
    Xout2[(size_t)wid * 64 + lane] = acc;
    if (pool_flag) {
        int g = batch[wid];
        atomicAdd(&pooled[g * DIM + 2 * lane], acc.x);
        atomicAdd(&pooled[g * DIM + 2 * lane + 1], acc.y);
    }
}

__global__ void final_kernel(const float* __restrict__ pooled, const float* __restrict__ Wf,
                             const float* __restrict__ bf, float* __restrict__ y) {
    int wid = (blockIdx.x * blockDim.x + threadIdx.x) >> 6;
    int lane = threadIdx.x & 63;
    if (wid >= N_GRAPHS) return;
    float2 p = *(const float2*)&pooled[wid * DIM + 2 * lane];
    float2 w = *(const float2*)&Wf[2 * lane];
    float v = p.x * w.x + p.y * w.y;
    for (int off = 32; off; off >>= 1) v += __shfl_down(v, off);
    if (lane == 0) y[wid] = v + bf[0];
}

extern "C" void kernel_launch(void* const* d_in, const int* in_sizes, int n_in,
                              void* d_out, int out_size, void* d_ws, size_t ws_size,
                              hipStream_t stream) {
    const float* x       = (const float*)d_in[0];
    const int*   ei      = (const int*)d_in[1];
    const int*   batch   = (const int*)d_in[2];
    const float* Ws      = (const float*)d_in[3];
    const float* att_src = (const float*)d_in[4];
    const float* att_dst = (const float*)d_in[5];
    const float* biases  = (const float*)d_in[6];
    const float* Wf      = (const float*)d_in[7];
    const float* bf      = (const float*)d_in[8];
    float* y = (float*)d_out;

    char* p = (char*)d_ws;
    auto alloc = [&](size_t bytes) -> void* {
        void* r = (void*)p;
        p += (bytes + 255) & ~(size_t)255;
        return r;
    };
    float* xA      = (float*)alloc((size_t)N_NODES * DIM * 4);
    float* xB      = (float*)alloc((size_t)N_NODES * DIM * 4);
    float* h       = (float*)alloc((size_t)N_NODES * DIM * 4);
    float* alphab  = (float*)alloc((size_t)E_TOT * 4);
    float* wcsr    = (float*)alloc((size_t)E_TOT * 4);
    int*   csr_src = (int*)alloc((size_t)E_TOT * 4);
    int*   csr_pos = (int*)alloc((size_t)E_TOT * 4);
    int*   deg     = (int*)alloc((size_t)N_NODES * 4);
    int*   fillc   = (int*)alloc((size_t)N_NODES * 4);
    int*   row_ptr = (int*)alloc((size_t)(N_NODES + 1) * 4);
    int*   blksum  = (int*)alloc(256 * 4);
    unsigned* menc3 = (unsigned*)alloc((size_t)3 * N_NODES * 4);
    float* ssum3   = (float*)alloc((size_t)3 * N_NODES * 4);
    float* pooled  = (float*)alloc((size_t)N_GRAPHS * DIM * 4);
    float* s1      = (float*)alloc((size_t)N_NODES * 4);
    float* s2      = (float*)alloc((size_t)N_NODES * 4);

    const int BN = 256;
    const int gN   = (N_NODES + BN - 1) / BN;
    const int gE   = (E_TOT + BN - 1) / BN;
    const int gI   = (3 * N_NODES + BN - 1) / BN;
    const int gNW  = (N_NODES * 64 + BN - 1) / BN;  // wave per node
    const int nblk = gN;

    zero_kernel<<<gI, BN, 0, stream>>>(deg, fillc, pooled, menc3, ssum3);
    count_kernel<<<gE, BN, 0, stream>>>(ei, deg);
    scan1_kernel<<<nblk, BN, 0, stream>>>(deg, row_ptr, blksum, N_NODES);
    scan2_kernel<<<1, BN, 0, stream>>>(blksum, nblk);
    scan3_kernel<<<gN, BN, 0, stream>>>(row_ptr, blksum, N_NODES);
    fill_kernel<<<gE, BN, 0, stream>>>(ei, row_ptr, fillc, csr_src, csr_pos);

    const float* xin = x;
    float* xout = xA;
    for (int l = 0; l < 3; ++l) {
        const float* W  = Ws + (size_t)l * DIM * DIM;
        const float* as = att_src + (size_t)l * DIM;
        const float* ad = att_dst + (size_t)l * DIM;
        const float* b  = biases + (size_t)l * DIM;
        unsigned* menc = menc3 + (size_t)l * N_NODES;
        float* ssum    = ssum3 + (size_t)l * N_NODES;

        gemm_dots_kernel<<<(N_NODES + 127) / 128, BN, 0, stream>>>(xin, W, as, ad, h, s1, s2, N_NODES);
        edge1_kernel<<<gE, BN, 0, stream>>>(ei, s1, s2, alphab, menc);
        edge2_kernel<<<gE, BN, 0, stream>>>(ei, alphab, menc, ssum, csr_pos, wcsr);
        agg_kernel<<<gNW, BN, 0, stream>>>((const float2*)h, wcsr, csr_src, row_ptr,
                                           ssum, b, (float2*)xout, batch, pooled,
                                           (l == 2) ? 1 : 0, N_NODES);
        xin = xout;
        xout = (l == 0) ? xB : xA;
    }

    final_kernel<<<(N_GRAPHS * 64 + BN - 1) / BN, BN, 0, stream>>>(pooled, Wf, bf, y);
    (void)ws_size; (void)n_in; (void)in_sizes; (void)out_size;
}

// Round 4
// 582.478 us; speedup vs baseline: 1.8354x; 1.6174x over previous
//
#include <hip/hip_runtime.h>
#include <hip/hip_bf16.h>

#define N_NODES 50000
#define DIM 128
#define N_GRAPHS 64
#define E_RAW 800000
#define E_TOT 850000
#define E_CAP 1200000   // E_TOT + 7*N_NODES : max padded CSR size
#define NEG_SLOPE 0.2f

typedef unsigned int uint;

// round-to-nearest-even f32 -> bf16 (as uint16 in low bits)
__device__ __forceinline__ uint bf16r(float f) {
    uint u = __float_as_uint(f);
    return (u + 0x7fffu + ((u >> 16) & 1u)) >> 16;
}

// ---------- init: deg/fillc/pooled zero, csr_src = -1 over padded capacity ----------
__global__ void init_kernel(int* deg, int* fillc, float* pooled, int* csr_src) {
    int i = blockIdx.x * blockDim.x + threadIdx.x;
    if (i < N_NODES) { deg[i] = 0; fillc[i] = 0; }
    if (i < N_GRAPHS * DIM) pooled[i] = 0.f;
    if (i < E_CAP) csr_src[i] = -1;
}

// ---------- CSR build (dst-sorted, segments padded to multiple of 8) ----------
__global__ void count_kernel(const int* __restrict__ ei, int* __restrict__ deg) {
    int e = blockIdx.x * blockDim.x + threadIdx.x;
    if (e >= E_TOT) return;
    int dst = (e < E_RAW) ? ei[E_RAW + e] : (e - E_RAW);
    atomicAdd(&deg[dst], 1);
}

__global__ void scan1_kernel(const int* __restrict__ deg, int* __restrict__ excl,
                             int* __restrict__ blksum, int n) {
    __shared__ int lds[256];
    int t = threadIdx.x;
    int i = blockIdx.x * 256 + t;
    int v = (i < n) ? ((deg[i] + 7) & ~7) : 0;   // padded degree
    lds[t] = v;
    __syncthreads();
    int incl = v;
    for (int off = 1; off < 256; off <<= 1) {
        int y = (t >= off) ? lds[t - off] : 0;
        __syncthreads();
        incl += y;
        lds[t] = incl;
        __syncthreads();
    }
    if (i < n) excl[i] = incl - v;
    if (t == 255) blksum[blockIdx.x] = incl;
}

__global__ void scan2_kernel(int* __restrict__ blksum, int* __restrict__ row_ptr, int nblk) {
    __shared__ int lds[256];
    int t = threadIdx.x;
    int v = (t < nblk) ? blksum[t] : 0;
    lds[t] = v;
    __syncthreads();
    int incl = v;
    for (int off = 1; off < 256; off <<= 1) {
        int y = (t >= off) ? lds[t - off] : 0;
        __syncthreads();
        incl += y;
        lds[t] = incl;
        __syncthreads();
    }
    if (t < nblk) blksum[t] = incl - v;            // exclusive block offsets
    if (t == nblk - 1) row_ptr[N_NODES] = incl;    // total padded size
}

__global__ void scan3_kernel(int* __restrict__ row_ptr, const int* __restrict__ blksum, int n) {
    int i = blockIdx.x * blockDim.x + threadIdx.x;
    if (i < n) row_ptr[i] += blksum[i >> 8];
}

__global__ void fill_kernel(const int* __restrict__ ei, const int* __restrict__ row_ptr,
                            int* __restrict__ fillc, int* __restrict__ csr_src) {
    int e = blockIdx.x * blockDim.x + threadIdx.x;
    if (e >= E_TOT) return;
    int src, dst;
    if (e < E_RAW) { src = ei[e]; dst = ei[E_RAW + e]; }
    else           { src = dst = e - E_RAW; }
    int slot = row_ptr[dst] + atomicAdd(&fillc[dst], 1);
    csr_src[slot] = src;
}

// ---------- GEMM + fused attention dots; H written as packed bf16 ----------
__global__ __launch_bounds__(256) void gemm_dots_kernel(
    const float* __restrict__ X, const float* __restrict__ W,
    const float* __restrict__ asrc, const float* __restrict__ adst,
    uint* __restrict__ Hb, float* __restrict__ s1, float* __restrict__ s2, int nrows) {
    __shared__ float Wl[DIM][DIM];
    int t = threadIdx.x;
    for (int i = t; i < DIM * DIM / 4; i += 256)
        ((float4*)&Wl[0][0])[i] = ((const float4*)W)[i];
    __syncthreads();

    int tx = t & 15, ty = t >> 4;
    int row0 = blockIdx.x * 128 + ty * 8;
    int col0 = tx * 8;
    float acc[8][8];
#pragma unroll
    for (int r = 0; r < 8; ++r)
#pragma unroll
        for (int c = 0; c < 8; ++c) acc[r][c] = 0.f;

    for (int k = 0; k < DIM; k += 4) {
        float4 xr[8];
#pragma unroll
        for (int r = 0; r < 8; ++r) {
            int row = row0 + r;
            xr[r] = (row < nrows) ? *(const float4*)&X[row * DIM + k]
                                  : make_float4(0.f, 0.f, 0.f, 0.f);
        }
#pragma unroll
        for (int kk = 0; kk < 4; ++kk) {
            float w0[8];
#pragma unroll
            for (int c = 0; c < 8; ++c) w0[c] = Wl[k + kk][col0 + c];
#pragma unroll
            for (int r = 0; r < 8; ++r) {
                float xv = (kk == 0) ? xr[r].x : (kk == 1) ? xr[r].y : (kk == 2) ? xr[r].z : xr[r].w;
#pragma unroll
                for (int c = 0; c < 8; ++c) acc[r][c] = fmaf(xv, w0[c], acc[r][c]);
            }
        }
    }

    float a1r[8], a2r[8];
#pragma unroll
    for (int c = 0; c < 8; ++c) { a1r[c] = asrc[col0 + c]; a2r[c] = adst[col0 + c]; }

#pragma unroll
    for (int r = 0; r < 8; ++r) {
        int row = row0 + r;
        if (row < nrows) {
            uint us0 = bf16r(acc[r][0]) | (bf16r(acc[r][1]) << 16);
            uint us1 = bf16r(acc[r][2]) | (bf16r(acc[r][3]) << 16);
            uint us2 = bf16r(acc[r][4]) | (bf16r(acc[r][5]) << 16);
            uint us3 = bf16r(acc[r][6]) | (bf16r(acc[r][7]) << 16);
            *(uint4*)&Hb[(size_t)row * 64 + (col0 >> 1)] = make_uint4(us0, us1, us2, us3);
        }
        float p1 = 0.f, p2 = 0.f;
#pragma unroll
        for (int c = 0; c < 8; ++c) { p1 = fmaf(acc[r][c], a1r[c], p1); p2 = fmaf(acc[r][c], a2r[c], p2); }
#pragma unroll
        for (int m = 1; m < 16; m <<= 1) { p1 += __shfl_xor(p1, m); p2 += __shfl_xor(p2, m); }
        if (tx == 0 && row < nrows) { s1[row] = p1; s2[row] = p2; }
    }
}

// ---------- fused softmax + aggregation: one wave per dst node ----------
// w = exp(leakyrelu(s1[src]+s2[dst])) computed in-register (softmax is
// shift-invariant; |alpha| small enough that exp cannot overflow fp32).
// H rows are bf16-packed (256 B) -> half the 64B-line fetch volume.
// Pad slots have csr_src = -1 -> w forced to 0, gather clamped to hot row 0.
__global__ __launch_bounds__(256) void agg_kernel(
    const uint* __restrict__ Hb, const int* __restrict__ csr_src,
    const int* __restrict__ row_ptr, const float* __restrict__ s1,
    const float* __restrict__ s2n, const float* __restrict__ bias,
    float2* __restrict__ Xout2, const int* __restrict__ batch,
    float* __restrict__ pooled, int pool_flag, int n) {
    int wid = (blockIdx.x * blockDim.x + threadIdx.x) >> 6;
    int lane = threadIdx.x & 63;
    if (wid >= n) return;
    int beg = row_ptr[wid], end = row_ptr[wid + 1];
    float s2v = s2n[wid];
    float2 acc = make_float2(0.f, 0.f);
    float wsum = 0.f;

    for (int s = beg; s < end; s += 8) {
        int4 a = *(const int4*)&csr_src[s];
        int4 b = *(const int4*)&csr_src[s + 4];
        int sn[8] = {a.x, a.y, a.z, a.w, b.x, b.y, b.z, b.w};
        uint hv[8];
#pragma unroll
        for (int j = 0; j < 8; ++j) {
            int r = (sn[j] < 0) ? 0 : sn[j];
            hv[j] = Hb[(size_t)r * 64 + lane];
        }
        float w[8];
#pragma unroll
        for (int j = 0; j < 8; ++j) {
            int r = (sn[j] < 0) ? 0 : sn[j];
            float al = s1[r] + s2v;
            al = (al > 0.f) ? al : NEG_SLOPE * al;
            float e = __expf(al);
            w[j] = (sn[j] < 0) ? 0.f : e;
            wsum += w[j];
        }
#pragma unroll
        for (int j = 0; j < 8; ++j) {
            float lo = __uint_as_float(hv[j] << 16);
            float hi = __uint_as_float(hv[j] & 0xffff0000u);
            acc.x = fmaf(w[j], lo, acc.x);
            acc.y = fmaf(w[j], hi, acc.y);
        }
    }

    float inv = 1.f / (wsum + 1e-16f);
    float2 b2 = ((const float2*)bias)[lane];
    acc.x = fmaxf(fmaf(acc.x, inv, b2.x), 0.f);
    acc.y = fmaxf(fmaf(acc.y, inv, b2.y), 0.f);
    Xout2[(size_t)wid * 64 + lane] = acc;
    if (pool_flag) {
        int g = batch[wid];
        atomicAdd(&pooled[g * DIM + 2 * lane], acc.x);
        atomicAdd(&pooled[g * DIM + 2 * lane + 1], acc.y);
    }
}

__global__ void final_kernel(const float* __restrict__ pooled, const float* __restrict__ Wf,
                             const float* __restrict__ bf, float* __restrict__ y) {
    int wid = (blockIdx.x * blockDim.x + threadIdx.x) >> 6;
    int lane = threadIdx.x & 63;
    if (wid >= N_GRAPHS) return;
    float2 p = *(const float2*)&pooled[wid * DIM + 2 * lane];
    float2 w = *(const float2*)&Wf[2 * lane];
    float v = p.x * w.x + p.y * w.y;
    for (int off = 32; off; off >>= 1) v += __shfl_down(v, off);
    if (lane == 0) y[wid] = v + bf[0];
}

extern "C" void kernel_launch(void* const* d_in, const int* in_sizes, int n_in,
                              void* d_out, int out_size, void* d_ws, size_t ws_size,
                              hipStream_t stream) {
    const float* x       = (const float*)d_in[0];
    const int*   ei      = (const int*)d_in[1];
    const int*   batch   = (const int*)d_in[2];
    const float* Ws      = (const float*)d_in[3];
    const float* att_src = (const float*)d_in[4];
    const float* att_dst = (const float*)d_in[5];
    const float* biases  = (const float*)d_in[6];
    const float* Wf      = (const float*)d_in[7];
    const float* bf      = (const float*)d_in[8];
    float* y = (float*)d_out;

    char* p = (char*)d_ws;
    auto alloc = [&](size_t bytes) -> void* {
        void* r = (void*)p;
        p += (bytes + 255) & ~(size_t)255;
        return r;
    };
    float* xA      = (float*)alloc((size_t)N_NODES * DIM * 4);
    float* xB      = (float*)alloc((size_t)N_NODES * DIM * 4);
    uint*  Hb      = (uint*)alloc((size_t)N_NODES * 64 * 4);   // bf16x2 packed
    int*   csr_src = (int*)alloc((size_t)E_CAP * 4);
    int*   deg     = (int*)alloc((size_t)N_NODES * 4);
    int*   fillc   = (int*)alloc((size_t)N_NODES * 4);
    int*   row_ptr = (int*)alloc((size_t)(N_NODES + 1) * 4);
    int*   blksum  = (int*)alloc(256 * 4);
    float* s1      = (float*)alloc((size_t)N_NODES * 4);
    float* s2      = (float*)alloc((size_t)N_NODES * 4);
    float* pooled  = (float*)alloc((size_t)N_GRAPHS * DIM * 4);

    const int BN = 256;
    const int gN   = (N_NODES + BN - 1) / BN;
    const int gE   = (E_TOT + BN - 1) / BN;
    const int gI   = (E_CAP + BN - 1) / BN;
    const int gNW  = (N_NODES * 64 + BN - 1) / BN;  // one wave per node
    const int nblk = gN;

    init_kernel<<<gI, BN, 0, stream>>>(deg, fillc, pooled, csr_src);
    count_kernel<<<gE, BN, 0, stream>>>(ei, deg);
    scan1_kernel<<<nblk, BN, 0, stream>>>(deg, row_ptr, blksum, N_NODES);
    scan2_kernel<<<1, BN, 0, stream>>>(blksum, row_ptr, nblk);
    scan3_kernel<<<gN, BN, 0, stream>>>(row_ptr, blksum, N_NODES);
    fill_kernel<<<gE, BN, 0, stream>>>(ei, row_ptr, fillc, csr_src);

    const float* xin = x;
    float* xout = xA;
    for (int l = 0; l < 3; ++l) {
        const float* W  = Ws + (size_t)l * DIM * DIM;
        const float* as = att_src + (size_t)l * DIM;
        const float* ad = att_dst + (size_t)l * DIM;
        const float* b  = biases + (size_t)l * DIM;

        gemm_dots_kernel<<<(N_NODES + 127) / 128, BN, 0, stream>>>(xin, W, as, ad, Hb, s1, s2, N_NODES);
        agg_kernel<<<gNW, BN, 0, stream>>>(Hb, csr_src, row_ptr, s1, s2, b,
                                           (float2*)xout, batch, pooled,
                                           (l == 2) ? 1 : 0, N_NODES);
        xin = xout;
        xout = (l == 0) ? xB : xA;
    }

    final_kernel<<<(N_GRAPHS * 64 + BN - 1) / BN, BN, 0, stream>>>(pooled, Wf, bf, y);
    (void)ws_size; (void)n_in; (void)in_sizes; (void)out_size;
}